// Round 1
// 412.513 us; speedup vs baseline: 1.1464x; 1.1464x over previous
//
#include <hip/hip_runtime.h>
#include <math.h>

// ---------------------------------------------------------------------------
// CrossPath: dual cross-attention block, MI355X (gfx950).
//   B=4, N=2304, C=256, H=8, D=32, out = 2 x [B,C,96,96] float32
// Inputs float32 (runtime-sniffed). Internal: bf16 MFMA, fp32 accumulation.
// beta cancels in softmax. R8: v_cvt_pk_bf16_f32 for all f32->bf16 packing,
// scale*log2e folded into Q at QKV-GEMM epilogue (p = exp2(s) directly),
// register prefetch of next K/V chunk issued after the barrier (latency
// hidden under compute), merged attn (both directions, one dispatch),
// merged proj-GEMM / LN / upsample, x pre-converted to bf16 once.
// ---------------------------------------------------------------------------

typedef __attribute__((ext_vector_type(8))) short short8;   // 8 bf16 = 4 VGPRs
typedef __attribute__((ext_vector_type(4))) float f32x4;

#define MFMA16(a, b, c) __builtin_amdgcn_mfma_f32_16x16x32_bf16((a), (b), (c), 0, 0, 0)

__device__ __forceinline__ float bf2f(ushort u) {
    union { unsigned u; float f; } x; x.u = ((unsigned)u) << 16; return x.f;
}
__device__ __forceinline__ ushort f2bf(float f) {
    union { float f; unsigned u; } x; x.f = f;
    unsigned u = x.u;
    return (ushort)((u + 0x7fffu + ((u >> 16) & 1u)) >> 16);   // RNE
}
// HW packed RNE conversion: D = {bf16(b)<<16 | bf16(a)}
__device__ __forceinline__ unsigned cvt_pk_bf16(float a, float b) {
    unsigned r;
    asm("v_cvt_pk_bf16_f32 %0, %1, %2" : "=v"(r) : "v"(a), "v"(b));
    return r;
}

// ---------------------------------------------------------------------------
// Dtype sniffer: flag=1 means f32 inputs.
// ---------------------------------------------------------------------------
__global__ void sniff_kernel(const ushort* __restrict__ x, int* __restrict__ flag)
{
    int lane = threadIdx.x;
    ushort u = x[lane * 2];
    int e = (u >> 7) & 0xFF;
    int outlier = (e < 100 || e > 135) ? 1 : 0;
    unsigned long long m = __ballot(outlier);
    if (lane == 0) *flag = (__popcll(m) >= 16) ? 1 : 0;
}

// ---------------------------------------------------------------------------
// Canonicalize all 12 weight/param arrays to bf16 at fixed offsets in ws.
// ---------------------------------------------------------------------------
__global__ __launch_bounds__(256) void convert_params(
    const void* s0, const void* s1, const void* s2, const void* s3,
    const void* s4, const void* s5, const void* s6, const void* s7,
    const void* s8, const void* s9, const void* s10, const void* s11,
    ushort* __restrict__ dst, const int* __restrict__ flag)
{
    int idx = blockIdx.x * 256 + threadIdx.x;
    if (idx >= 525824) return;
    const void* src; int off;
    if      (idx < 65536)  { src = s0;  off = idx; }
    else if (idx < 196608) { src = s1;  off = idx - 65536; }
    else if (idx < 262144) { src = s2;  off = idx - 196608; }
    else if (idx < 393216) { src = s3;  off = idx - 262144; }
    else if (idx < 458752) { src = s4;  off = idx - 393216; }
    else if (idx < 524288) { src = s5;  off = idx - 458752; }
    else if (idx < 524544) { src = s6;  off = idx - 524288; }
    else if (idx < 524800) { src = s7;  off = idx - 524544; }
    else if (idx < 525056) { src = s8;  off = idx - 524800; }
    else if (idx < 525312) { src = s9;  off = idx - 525056; }
    else if (idx < 525568) { src = s10; off = idx - 525312; }
    else                   { src = s11; off = idx - 525568; }
    ushort v = (*flag) ? f2bf(((const float*)src)[off])
                       : ((const ushort*)src)[off];
    dst[idx] = v;
}

// ---------------------------------------------------------------------------
// Pre-convert x1/x2 -> bf16 once (8 elems/thread). Removes the f32 A-path
// from the QKV GEMM (which re-reads A 12x) entirely.
// ---------------------------------------------------------------------------
__global__ __launch_bounds__(256) void convert_x(
    const void* __restrict__ x1, const void* __restrict__ x2,
    ushort* __restrict__ o1, ushort* __restrict__ o2,
    const int* __restrict__ flag)
{
    int idx = blockIdx.x * 256 + threadIdx.x;      // 2304 blocks -> 589824 thr
    int which = idx >= 294912;
    int off = (which ? idx - 294912 : idx) * 8;
    const void* src = which ? x2 : x1;
    ushort* dst = which ? o2 : o1;
    if (*flag) {
        const float* p = (const float*)src + off;
        float4 a = *(const float4*)p;
        float4 c = *(const float4*)(p + 4);
        uint4 u;
        u.x = cvt_pk_bf16(a.x, a.y);
        u.y = cvt_pk_bf16(a.z, a.w);
        u.z = cvt_pk_bf16(c.x, c.y);
        u.w = cvt_pk_bf16(c.z, c.w);
        *(uint4*)(dst + off) = u;
    } else {
        *(uint4*)(dst + off) = *(const uint4*)((const ushort*)src + off);
    }
}

// ---------------------------------------------------------------------------
// GEMM: C[M,N] = A[M,K]*W[N,K]^T, bf16 MFMA 16x16x32, tile 64x64, 4 waves.
// Two stacked problems (rows [0,mhalf) use W/bias/Kh/Vt, rows [mhalf,M) use
// W2/bias2/Kh2/Vt2). mode 0: plain C (+bias/relu). mode 1 (merged QKV,
// N=768): col<256 -> Q row-major SCALED by scale*log2e; col<512 ->
// Kh[b][h][tok][32]; else -> Vt[b][h][d][2304].
// ---------------------------------------------------------------------------
__global__ __launch_bounds__(256) void gemm_bt(
    const void* __restrict__ Ain, const ushort* __restrict__ W,
    ushort* __restrict__ C, const ushort* __restrict__ bias,
    int M, int N, int K, int relu, const int* __restrict__ dflag, int a_ext,
    int mode, ushort* __restrict__ Kh, ushort* __restrict__ Vt,
    const ushort* __restrict__ W2, const ushort* __restrict__ bias2,
    ushort* __restrict__ Kh2, ushort* __restrict__ Vt2, int mhalf)
{
    __shared__ __align__(16) ushort As[64][40];
    __shared__ __align__(16) ushort Ws[64][40];

    const int m0 = blockIdx.x * 64;
    const int n0 = blockIdx.y * 64;
    const int tid = threadIdx.x;
    const int w = tid >> 6;
    const int lane = tid & 63;
    const int lm = lane & 15;
    const int quad = lane >> 4;
    const int a32 = a_ext ? *dflag : 0;

    const int side = (mhalf && m0 >= mhalf) ? 1 : 0;
    const ushort* Wu = side ? W2 : W;
    const ushort* bu = side ? bias2 : bias;
    ushort* Khu = side ? Kh2 : Kh;
    ushort* Vtu = side ? Vt2 : Vt;

    const f32x4 Z4 = {0.f, 0.f, 0.f, 0.f};
    f32x4 acc[4];
    for (int j = 0; j < 4; j++) acc[j] = Z4;

    const ushort* A16 = (const ushort*)Ain;
    const float*  A32 = (const float*)Ain;
    const int row = tid >> 2, off = (tid & 3) * 8;

    for (int k0 = 0; k0 < K; k0 += 32) {
        __syncthreads();
        if (a32) {
            const float* p0 = A32 + (size_t)(m0 + row) * K + k0 + off;
            float4 f0 = *(const float4*)p0;
            float4 f1 = *(const float4*)(p0 + 4);
            uint4 t0;
            t0.x = cvt_pk_bf16(f0.x, f0.y);
            t0.y = cvt_pk_bf16(f0.z, f0.w);
            t0.z = cvt_pk_bf16(f1.x, f1.y);
            t0.w = cvt_pk_bf16(f1.z, f1.w);
            *(uint4*)&As[row][off] = t0;
        } else {
            *(uint4*)&As[row][off] =
                *(const uint4*)(A16 + (size_t)(m0 + row) * K + k0 + off);
        }
        *(uint4*)&Ws[row][off] =
            *(const uint4*)(Wu + (size_t)(n0 + row) * K + k0 + off);
        __syncthreads();

        short8 af = *(const short8*)&As[w * 16 + lm][quad * 8];
        for (int nt = 0; nt < 4; nt++) {
            short8 wf = *(const short8*)&Ws[nt * 16 + lm][quad * 8];
            acc[nt] = MFMA16(af, wf, acc[nt]);
        }
    }

    const int grow = m0 + w * 16 + quad * 4;     // global C row (4 consecutive)
    const int grel = grow - (side ? mhalf : 0);  // row within half (Kh/Vt)
    if (mode == 1) {
        const float QSC = 0.17677669529663687f * 1.4426950408889634f;
        int bb = grel / 2304;
        int tok = grel - bb * 2304;              // 4-aligned; same bb for r=0..3
        for (int nt = 0; nt < 4; nt++) {
            int col = n0 + nt * 16 + lm;
            if (col < 256) {
                for (int r = 0; r < 4; r++)
                    C[(size_t)(grow + r) * 256 + col] = f2bf(acc[nt][r] * QSC);
            } else if (col < 512) {
                int c2 = col - 256, hh = c2 >> 5, d = c2 & 31;
                for (int r = 0; r < 4; r++)
                    Khu[(((size_t)bb * 8 + hh) * 2304 + tok + r) * 32 + d] = f2bf(acc[nt][r]);
            } else {
                int c2 = col - 512, hh = c2 >> 5, d = c2 & 31;
                uint2 o;
                o.x = cvt_pk_bf16(acc[nt][0], acc[nt][1]);
                o.y = cvt_pk_bf16(acc[nt][2], acc[nt][3]);
                *(uint2*)&Vtu[(((size_t)bb * 8 + hh) * 32 + d) * 2304 + tok] = o;
            }
        }
    } else {
        for (int nt = 0; nt < 4; nt++) {
            int col = n0 + nt * 16 + lm;
            float bv = bu ? bf2f(bu[col]) : 0.f;
            for (int r = 0; r < 4; r++) {
                float v = acc[nt][r] + bv;
                if (relu) v = fmaxf(v, 0.f);
                C[(size_t)(grow + r) * N + col] = f2bf(v);
            }
        }
    }
}

// ---------------------------------------------------------------------------
// Flash cross-attention, S^T form, no-max softmax (p = exp2(s), Q pre-scaled
// by scale*log2e in the QKV GEMM). Both directions in one dispatch
// (blockIdx.y>>5 selects side). Register prefetch of next K/V chunk issued
// after the second barrier so HBM latency hides under compute.
// Q:[B,2304,256]; Kh:[b][h][tok][32]; Vt:[b][h][d][2304]; O:[B,2304,256].
// ---------------------------------------------------------------------------
__global__ __launch_bounds__(256) void attn_kernel(
    const ushort* __restrict__ Qa, const ushort* __restrict__ Kha,
    const ushort* __restrict__ Vta, ushort* __restrict__ Oa,
    const ushort* __restrict__ Qb, const ushort* __restrict__ Khb2,
    const ushort* __restrict__ Vtb2, ushort* __restrict__ Ob)
{
    __shared__ __align__(16) ushort Ksh[64][40];   // [key][d]
    __shared__ __align__(16) ushort Vsh[32][72];   // [d][tok]
    __shared__ __align__(16) ushort Pl[4][16][80]; // per-wave P^T [q][key]

    const int qb = blockIdx.x;
    const int side = blockIdx.y >> 5;
    const int bh = blockIdx.y & 31;
    const ushort* Q  = side ? Qb   : Qa;
    const ushort* Kh = side ? Khb2 : Kha;
    const ushort* Vt = side ? Vtb2 : Vta;
    ushort* O        = side ? Ob   : Oa;

    const int b = bh >> 3;
    const int tid = threadIdx.x;
    const int w = tid >> 6, lane = tid & 63;
    const int lm = lane & 15, quad = lane >> 4;
    const f32x4 Z4 = {0.f, 0.f, 0.f, 0.f};

    // Q B-frag: lane holds Q[q=lm][d=quad*8+j] (persistent, pre-scaled)
    const int qrow = qb * 64 + w * 16 + lm;
    const int h = bh & 7;
    short8 qf = *(const short8*)(Q + ((size_t)b * 2304 + qrow) * 256 + h * 32 + quad * 8);

    f32x4 o_acc[2]; o_acc[0] = Z4; o_acc[1] = Z4;   // O^T[d=dt*16+quad*4+r][q=lm]
    float l = 0.f;                                   // per-lane partial denom

    const ushort* Khb = Kh + (size_t)bh * 2304 * 32;
    const ushort* Vtb = Vt + (size_t)bh * 32 * 2304;
    const int ks_row = tid >> 2, ks_off = (tid & 3) * 8;
    const int vs_row = tid >> 3, vs_off = (tid & 7) * 8;

    const ushort* kptr = Khb + (size_t)ks_row * 32 + ks_off;
    const ushort* vptr = Vtb + (size_t)vs_row * 2304 + vs_off;
    uint4 kreg = *(const uint4*)kptr;
    uint4 vreg = *(const uint4*)vptr;

    for (int kc = 0; kc < 36; kc++) {
        __syncthreads();
        *(uint4*)&Ksh[ks_row][ks_off] = kreg;
        *(uint4*)&Vsh[vs_row][vs_off] = vreg;
        __syncthreads();

        // issue next chunk's loads now: vmcnt drain happens at the NEXT
        // iteration's first barrier, after the whole compute phase.
        int nk = kc < 35 ? kc + 1 : 35;
        kreg = *(const uint4*)(kptr + (size_t)nk * 2048);
        vreg = *(const uint4*)(vptr + nk * 64);

        // S^T: tile t covers keys t*16+quad*4+r, col q=lm
        f32x4 s[4];
        for (int t = 0; t < 4; t++) {
            short8 kf = *(const short8*)&Ksh[t * 16 + lm][quad * 8];
            s[t] = MFMA16(kf, qf, Z4);
        }

        // p = exp2(s); accumulate per-lane l; pack via v_cvt_pk_bf16_f32.
        for (int t = 0; t < 4; t++) {
            float p0 = exp2f(s[t][0]);
            float p1 = exp2f(s[t][1]);
            float p2 = exp2f(s[t][2]);
            float p3 = exp2f(s[t][3]);
            l += (p0 + p1) + (p2 + p3);
            uint2 pk;
            pk.x = cvt_pk_bf16(p0, p1);
            pk.y = cvt_pk_bf16(p2, p3);
            *(uint2*)&Pl[w][lm][t * 16 + quad * 4] = pk;
        }
        asm volatile("s_waitcnt lgkmcnt(0)" ::: "memory");  // wave's P writes done

        // O^T += V^T * P^T per 32-key group
        for (int g = 0; g < 2; g++) {
            short8 pf = *(const short8*)&Pl[w][lm][g * 32 + quad * 8];
            for (int dt = 0; dt < 2; dt++) {
                short8 vf = *(const short8*)&Vsh[dt * 16 + lm][g * 32 + quad * 8];
                o_acc[dt] = MFMA16(vf, pf, o_acc[dt]);
            }
        }
    }

    // Quads hold disjoint key subsets for the same q=lm: reduce l across quads.
    l += __shfl_xor(l, 16, 64);
    l += __shfl_xor(l, 32, 64);
    float rl = 1.f / l;
    for (int dt = 0; dt < 2; dt++) {
        uint2 o;
        o.x = cvt_pk_bf16(o_acc[dt][0] * rl, o_acc[dt][1] * rl);
        o.y = cvt_pk_bf16(o_acc[dt][2] * rl, o_acc[dt][3] * rl);
        *(uint2*)(O + ((size_t)b * 2304 + qrow) * 256 + h * 32 + dt * 16 + quad * 4)
            = o;
    }
}

// ---------------------------------------------------------------------------
// LayerNorm over C=256, one wave per token. Both outputs merged (Z/Y
// contiguous); affine params selected by token half.
// ---------------------------------------------------------------------------
__global__ __launch_bounds__(256) void ln_kernel(
    const ushort* __restrict__ Z, const ushort* __restrict__ G1,
    const ushort* __restrict__ B1, const ushort* __restrict__ G2,
    const ushort* __restrict__ B2, ushort* __restrict__ Y)
{
    int tok = blockIdx.x * 4 + (threadIdx.x >> 6);
    int lane = threadIdx.x & 63;
    const ushort* G  = tok < 9216 ? G1 : G2;
    const ushort* Bt = tok < 9216 ? B1 : B2;
    const ushort* z = Z + (size_t)tok * 256 + lane * 4;
    ushort4 v = *(const ushort4*)z;
    float x0 = bf2f(v.x), x1 = bf2f(v.y), x2 = bf2f(v.z), x3 = bf2f(v.w);
    float s = x0 + x1 + x2 + x3;
    float q = x0 * x0 + x1 * x1 + x2 * x2 + x3 * x3;
    for (int off = 1; off < 64; off <<= 1) {
        s += __shfl_xor(s, off, 64);
        q += __shfl_xor(q, off, 64);
    }
    float mu = s * (1.f / 256.f);
    float var = q * (1.f / 256.f) - mu * mu;
    float rs = rsqrtf(var + 1e-5f);
    const ushort* g4 = G + lane * 4;
    const ushort* b4 = Bt + lane * 4;
    ushort4 o;
    o.x = f2bf((x0 - mu) * rs * bf2f(g4[0]) + bf2f(b4[0]));
    o.y = f2bf((x1 - mu) * rs * bf2f(g4[1]) + bf2f(b4[1]));
    o.z = f2bf((x2 - mu) * rs * bf2f(g4[2]) + bf2f(b4[2]));
    o.w = f2bf((x3 - mu) * rs * bf2f(g4[3]) + bf2f(b4[3]));
    *(ushort4*)(Y + (size_t)tok * 256 + lane * 4) = o;
}

// ---------------------------------------------------------------------------
// Bilinear 2x upsample, half-pixel + edge clamp. Y bf16 -> out FLOAT32.
// Merged: b spans 0..7 (Y1||Y2 contiguous, out1||out2 contiguous).
// ---------------------------------------------------------------------------
__global__ __launch_bounds__(256) void upsample_kernel(
    const ushort* __restrict__ Y, float* __restrict__ out)
{
    int idx = blockIdx.x * 256 + threadIdx.x;
    int oj = idx % 96;
    int t = idx / 96;
    int oi = t % 96;
    t /= 96;
    int c = t & 255;
    int b = t >> 8;                 // 0..7 across both outputs
    float fi = oi * 0.5f - 0.25f;
    float fj = oj * 0.5f - 0.25f;
    int i0 = (int)floorf(fi); float wi = fi - (float)i0;
    int j0 = (int)floorf(fj); float wj = fj - (float)j0;
    int i1 = i0 + 1 < 47 ? i0 + 1 : 47;
    int j1 = j0 + 1 < 47 ? j0 + 1 : 47;
    i0 = i0 > 0 ? i0 : 0;
    j0 = j0 > 0 ? j0 : 0;
    const ushort* base = Y + (size_t)b * 2304 * 256 + c;
    float v00 = bf2f(base[(size_t)(i0 * 48 + j0) * 256]);
    float v01 = bf2f(base[(size_t)(i0 * 48 + j1) * 256]);
    float v10 = bf2f(base[(size_t)(i1 * 48 + j0) * 256]);
    float v11 = bf2f(base[(size_t)(i1 * 48 + j1) * 256]);
    float val = (1.f - wi) * ((1.f - wj) * v00 + wj * v01)
              + wi * ((1.f - wj) * v10 + wj * v11);
    out[idx] = val;
}

// ---------------------------------------------------------------------------
extern "C" void kernel_launch(void* const* d_in, const int* in_sizes, int n_in,
                              void* d_out, int out_size, void* d_ws, size_t ws_size,
                              hipStream_t stream)
{
    (void)in_sizes; (void)n_in; (void)out_size; (void)ws_size;

    // ---- Buffer plan (stream-order-safe reuse; ~29.4 MB of ws) ----
    ushort* ws  = (ushort*)d_ws;
    ushort* Q1  = ws;                         // [9216,256]
    ushort* Q2  = Q1  + 2359296;              // contiguous with Q1
    ushort* KV1 = Q2  + 2359296;              // Kh1 + Vt1
    ushort* KV2 = KV1 + 4718592;              // Kh2 + Vt2
    ushort* wc  = KV2 + 4718592;              // canonical params
    int*    dflag = (int*)(wc + 525824);

    ushort* cqkv1w = wc;                      // [768,256] = q1w ++ kv1w
    ushort* cqkv2w = wc + 196608;             // [768,256] = q2w ++ kv2w
    ushort* cp1w  = wc + 393216;
    ushort* cp2w  = wc + 458752;
    ushort* cp1b  = wc + 524288;
    ushort* cp2b  = wc + 524544;
    ushort* cg1   = wc + 524800;
    ushort* cb1   = wc + 525056;
    ushort* cg2   = wc + 525312;
    ushort* cb2   = wc + 525568;

    float*  outf = (float*)d_out;
    ushort* O1  = (ushort*)d_out;             // bf16 staging (dead pre-upsample)
    ushort* O2  = O1 + 2359296;               // contiguous with O1
    ushort* Xb1 = O2 + 2359296;               // bf16 x1 (dead after QKV gemm)
    ushort* Xb2 = Xb1 + 2359296;              // contiguous with Xb1
    ushort* Z1  = KV2;                        // KV2 dead after attn (launch order)
    ushort* Z2  = KV2 + 2359296;              // contiguous with Z1
    ushort* Y1  = Q1;                         // Q1/Q2 dead after attn
    (void)Q2; (void)O2; (void)Xb2; (void)Z2;

    dim3 blk(256);
    sniff_kernel<<<dim3(1), dim3(64), 0, stream>>>((const ushort*)d_in[0], dflag);
    convert_params<<<dim3(2054), blk, 0, stream>>>(
        d_in[2], d_in[3], d_in[4], d_in[5], d_in[8], d_in[10],
        d_in[9], d_in[11], d_in[12], d_in[13], d_in[14], d_in[15],
        wc, dflag);
    convert_x<<<dim3(2304), blk, 0, stream>>>(d_in[0], d_in[1], Xb1, Xb2, dflag);

    // Merged Q+KV projections for BOTH inputs (M=18432, N=768):
    // Q scaled by scale*log2e, Kh per-head, Vt transposed.
    gemm_bt<<<dim3(288, 12), blk, 0, stream>>>(Xb1, cqkv1w, Q1, nullptr,
        18432, 768, 256, 0, dflag, 0, 1, KV1, KV1 + 2359296,
        cqkv2w, nullptr, KV2, KV2 + 2359296, 9216);

    // Both cross attentions in one dispatch (grid.y 0..31 = x1->x2 side,
    // 32..63 = x2->x1 side).
    attn_kernel<<<dim3(36, 64), blk, 0, stream>>>(
        Q1, KV2, KV2 + 2359296, O1,
        Q2, KV1, KV1 + 2359296, O2);

    // Merged output projection + bias + ReLU (M=18432).
    gemm_bt<<<dim3(288, 4), blk, 0, stream>>>(O1, cp1w, Z1, cp1b,
        18432, 256, 256, 1, dflag, 0, 0, nullptr, nullptr,
        cp2w, cp2b, nullptr, nullptr, 9216);

    // Merged LayerNorm (18432 tokens).
    ln_kernel<<<dim3(4608), blk, 0, stream>>>(Z1, cg1, cb1, cg2, cb2, Y1);

    // Merged bilinear 2x upsample into d_out (float32, both outputs).
    upsample_kernel<<<dim3(73728), blk, 0, stream>>>(Y1, outf);
}

// Round 2
// 295.532 us; speedup vs baseline: 1.6002x; 1.3958x over previous
//
#include <hip/hip_runtime.h>
#include <math.h>

// ---------------------------------------------------------------------------
// CrossPath: dual cross-attention block, MI355X (gfx950).
//   B=4, N=2304, C=256, H=8, D=32, out = 2 x [B,C,96,96] float32
// Inputs float32 (runtime-sniffed). Internal: bf16 MFMA, fp32 accumulation.
// R9: LN fused with transpose (lnt_kernel) producing channel-major
// Yt[bc][48*48] so the bilinear upsample reads spatially-contiguous rows
// (old layout caused ~32 cache lines per gather load -> 138 us dispatch).
// Upsample now emits an oj-pair per thread as one float2 store.
// ---------------------------------------------------------------------------

typedef __attribute__((ext_vector_type(8))) short short8;   // 8 bf16 = 4 VGPRs
typedef __attribute__((ext_vector_type(4))) float f32x4;

#define MFMA16(a, b, c) __builtin_amdgcn_mfma_f32_16x16x32_bf16((a), (b), (c), 0, 0, 0)

__device__ __forceinline__ float bf2f(ushort u) {
    union { unsigned u; float f; } x; x.u = ((unsigned)u) << 16; return x.f;
}
__device__ __forceinline__ ushort f2bf(float f) {
    union { float f; unsigned u; } x; x.f = f;
    unsigned u = x.u;
    return (ushort)((u + 0x7fffu + ((u >> 16) & 1u)) >> 16);   // RNE
}
// HW packed RNE conversion: D = {bf16(b)<<16 | bf16(a)}
__device__ __forceinline__ unsigned cvt_pk_bf16(float a, float b) {
    unsigned r;
    asm("v_cvt_pk_bf16_f32 %0, %1, %2" : "=v"(r) : "v"(a), "v"(b));
    return r;
}

// ---------------------------------------------------------------------------
// Dtype sniffer: flag=1 means f32 inputs.
// ---------------------------------------------------------------------------
__global__ void sniff_kernel(const ushort* __restrict__ x, int* __restrict__ flag)
{
    int lane = threadIdx.x;
    ushort u = x[lane * 2];
    int e = (u >> 7) & 0xFF;
    int outlier = (e < 100 || e > 135) ? 1 : 0;
    unsigned long long m = __ballot(outlier);
    if (lane == 0) *flag = (__popcll(m) >= 16) ? 1 : 0;
}

// ---------------------------------------------------------------------------
// Canonicalize all 12 weight/param arrays to bf16 at fixed offsets in ws.
// ---------------------------------------------------------------------------
__global__ __launch_bounds__(256) void convert_params(
    const void* s0, const void* s1, const void* s2, const void* s3,
    const void* s4, const void* s5, const void* s6, const void* s7,
    const void* s8, const void* s9, const void* s10, const void* s11,
    ushort* __restrict__ dst, const int* __restrict__ flag)
{
    int idx = blockIdx.x * 256 + threadIdx.x;
    if (idx >= 525824) return;
    const void* src; int off;
    if      (idx < 65536)  { src = s0;  off = idx; }
    else if (idx < 196608) { src = s1;  off = idx - 65536; }
    else if (idx < 262144) { src = s2;  off = idx - 196608; }
    else if (idx < 393216) { src = s3;  off = idx - 262144; }
    else if (idx < 458752) { src = s4;  off = idx - 393216; }
    else if (idx < 524288) { src = s5;  off = idx - 458752; }
    else if (idx < 524544) { src = s6;  off = idx - 524288; }
    else if (idx < 524800) { src = s7;  off = idx - 524544; }
    else if (idx < 525056) { src = s8;  off = idx - 524800; }
    else if (idx < 525312) { src = s9;  off = idx - 525056; }
    else if (idx < 525568) { src = s10; off = idx - 525312; }
    else                   { src = s11; off = idx - 525568; }
    ushort v = (*flag) ? f2bf(((const float*)src)[off])
                       : ((const ushort*)src)[off];
    dst[idx] = v;
}

// ---------------------------------------------------------------------------
// Pre-convert x1/x2 -> bf16 once (8 elems/thread).
// ---------------------------------------------------------------------------
__global__ __launch_bounds__(256) void convert_x(
    const void* __restrict__ x1, const void* __restrict__ x2,
    ushort* __restrict__ o1, ushort* __restrict__ o2,
    const int* __restrict__ flag)
{
    int idx = blockIdx.x * 256 + threadIdx.x;      // 2304 blocks -> 589824 thr
    int which = idx >= 294912;
    int off = (which ? idx - 294912 : idx) * 8;
    const void* src = which ? x2 : x1;
    ushort* dst = which ? o2 : o1;
    if (*flag) {
        const float* p = (const float*)src + off;
        float4 a = *(const float4*)p;
        float4 c = *(const float4*)(p + 4);
        uint4 u;
        u.x = cvt_pk_bf16(a.x, a.y);
        u.y = cvt_pk_bf16(a.z, a.w);
        u.z = cvt_pk_bf16(c.x, c.y);
        u.w = cvt_pk_bf16(c.z, c.w);
        *(uint4*)(dst + off) = u;
    } else {
        *(uint4*)(dst + off) = *(const uint4*)((const ushort*)src + off);
    }
}

// ---------------------------------------------------------------------------
// GEMM: C[M,N] = A[M,K]*W[N,K]^T, bf16 MFMA 16x16x32, tile 64x64, 4 waves.
// Two stacked problems (rows [0,mhalf) use W/bias/Kh/Vt, rows [mhalf,M) use
// W2/bias2/Kh2/Vt2). mode 0: plain C (+bias/relu). mode 1 (merged QKV,
// N=768): col<256 -> Q row-major SCALED by scale*log2e; col<512 ->
// Kh[b][h][tok][32]; else -> Vt[b][h][d][2304].
// ---------------------------------------------------------------------------
__global__ __launch_bounds__(256) void gemm_bt(
    const void* __restrict__ Ain, const ushort* __restrict__ W,
    ushort* __restrict__ C, const ushort* __restrict__ bias,
    int M, int N, int K, int relu, const int* __restrict__ dflag, int a_ext,
    int mode, ushort* __restrict__ Kh, ushort* __restrict__ Vt,
    const ushort* __restrict__ W2, const ushort* __restrict__ bias2,
    ushort* __restrict__ Kh2, ushort* __restrict__ Vt2, int mhalf)
{
    __shared__ __align__(16) ushort As[64][40];
    __shared__ __align__(16) ushort Ws[64][40];

    const int m0 = blockIdx.x * 64;
    const int n0 = blockIdx.y * 64;
    const int tid = threadIdx.x;
    const int w = tid >> 6;
    const int lane = tid & 63;
    const int lm = lane & 15;
    const int quad = lane >> 4;
    const int a32 = a_ext ? *dflag : 0;

    const int side = (mhalf && m0 >= mhalf) ? 1 : 0;
    const ushort* Wu = side ? W2 : W;
    const ushort* bu = side ? bias2 : bias;
    ushort* Khu = side ? Kh2 : Kh;
    ushort* Vtu = side ? Vt2 : Vt;

    const f32x4 Z4 = {0.f, 0.f, 0.f, 0.f};
    f32x4 acc[4];
    for (int j = 0; j < 4; j++) acc[j] = Z4;

    const ushort* A16 = (const ushort*)Ain;
    const float*  A32 = (const float*)Ain;
    const int row = tid >> 2, off = (tid & 3) * 8;

    for (int k0 = 0; k0 < K; k0 += 32) {
        __syncthreads();
        if (a32) {
            const float* p0 = A32 + (size_t)(m0 + row) * K + k0 + off;
            float4 f0 = *(const float4*)p0;
            float4 f1 = *(const float4*)(p0 + 4);
            uint4 t0;
            t0.x = cvt_pk_bf16(f0.x, f0.y);
            t0.y = cvt_pk_bf16(f0.z, f0.w);
            t0.z = cvt_pk_bf16(f1.x, f1.y);
            t0.w = cvt_pk_bf16(f1.z, f1.w);
            *(uint4*)&As[row][off] = t0;
        } else {
            *(uint4*)&As[row][off] =
                *(const uint4*)(A16 + (size_t)(m0 + row) * K + k0 + off);
        }
        *(uint4*)&Ws[row][off] =
            *(const uint4*)(Wu + (size_t)(n0 + row) * K + k0 + off);
        __syncthreads();

        short8 af = *(const short8*)&As[w * 16 + lm][quad * 8];
        for (int nt = 0; nt < 4; nt++) {
            short8 wf = *(const short8*)&Ws[nt * 16 + lm][quad * 8];
            acc[nt] = MFMA16(af, wf, acc[nt]);
        }
    }

    const int grow = m0 + w * 16 + quad * 4;     // global C row (4 consecutive)
    const int grel = grow - (side ? mhalf : 0);  // row within half (Kh/Vt)
    if (mode == 1) {
        const float QSC = 0.17677669529663687f * 1.4426950408889634f;
        int bb = grel / 2304;
        int tok = grel - bb * 2304;              // 4-aligned; same bb for r=0..3
        for (int nt = 0; nt < 4; nt++) {
            int col = n0 + nt * 16 + lm;
            if (col < 256) {
                for (int r = 0; r < 4; r++)
                    C[(size_t)(grow + r) * 256 + col] = f2bf(acc[nt][r] * QSC);
            } else if (col < 512) {
                int c2 = col - 256, hh = c2 >> 5, d = c2 & 31;
                for (int r = 0; r < 4; r++)
                    Khu[(((size_t)bb * 8 + hh) * 2304 + tok + r) * 32 + d] = f2bf(acc[nt][r]);
            } else {
                int c2 = col - 512, hh = c2 >> 5, d = c2 & 31;
                uint2 o;
                o.x = cvt_pk_bf16(acc[nt][0], acc[nt][1]);
                o.y = cvt_pk_bf16(acc[nt][2], acc[nt][3]);
                *(uint2*)&Vtu[(((size_t)bb * 8 + hh) * 32 + d) * 2304 + tok] = o;
            }
        }
    } else {
        for (int nt = 0; nt < 4; nt++) {
            int col = n0 + nt * 16 + lm;
            float bv = bu ? bf2f(bu[col]) : 0.f;
            for (int r = 0; r < 4; r++) {
                float v = acc[nt][r] + bv;
                if (relu) v = fmaxf(v, 0.f);
                C[(size_t)(grow + r) * N + col] = f2bf(v);
            }
        }
    }
}

// ---------------------------------------------------------------------------
// Flash cross-attention, S^T form, no-max softmax (p = exp2(s), Q pre-scaled
// by scale*log2e in the QKV GEMM). Both directions in one dispatch.
// ---------------------------------------------------------------------------
__global__ __launch_bounds__(256) void attn_kernel(
    const ushort* __restrict__ Qa, const ushort* __restrict__ Kha,
    const ushort* __restrict__ Vta, ushort* __restrict__ Oa,
    const ushort* __restrict__ Qb, const ushort* __restrict__ Khb2,
    const ushort* __restrict__ Vtb2, ushort* __restrict__ Ob)
{
    __shared__ __align__(16) ushort Ksh[64][40];   // [key][d]
    __shared__ __align__(16) ushort Vsh[32][72];   // [d][tok]
    __shared__ __align__(16) ushort Pl[4][16][80]; // per-wave P^T [q][key]

    const int qb = blockIdx.x;
    const int side = blockIdx.y >> 5;
    const int bh = blockIdx.y & 31;
    const ushort* Q  = side ? Qb   : Qa;
    const ushort* Kh = side ? Khb2 : Kha;
    const ushort* Vt = side ? Vtb2 : Vta;
    ushort* O        = side ? Ob   : Oa;

    const int b = bh >> 3;
    const int tid = threadIdx.x;
    const int w = tid >> 6, lane = tid & 63;
    const int lm = lane & 15, quad = lane >> 4;
    const f32x4 Z4 = {0.f, 0.f, 0.f, 0.f};

    // Q B-frag: lane holds Q[q=lm][d=quad*8+j] (persistent, pre-scaled)
    const int qrow = qb * 64 + w * 16 + lm;
    const int h = bh & 7;
    short8 qf = *(const short8*)(Q + ((size_t)b * 2304 + qrow) * 256 + h * 32 + quad * 8);

    f32x4 o_acc[2]; o_acc[0] = Z4; o_acc[1] = Z4;   // O^T[d=dt*16+quad*4+r][q=lm]
    float l = 0.f;                                   // per-lane partial denom

    const ushort* Khb = Kh + (size_t)bh * 2304 * 32;
    const ushort* Vtb = Vt + (size_t)bh * 32 * 2304;
    const int ks_row = tid >> 2, ks_off = (tid & 3) * 8;
    const int vs_row = tid >> 3, vs_off = (tid & 7) * 8;

    const ushort* kptr = Khb + (size_t)ks_row * 32 + ks_off;
    const ushort* vptr = Vtb + (size_t)vs_row * 2304 + vs_off;
    uint4 kreg = *(const uint4*)kptr;
    uint4 vreg = *(const uint4*)vptr;

    for (int kc = 0; kc < 36; kc++) {
        __syncthreads();
        *(uint4*)&Ksh[ks_row][ks_off] = kreg;
        *(uint4*)&Vsh[vs_row][vs_off] = vreg;
        __syncthreads();

        // issue next chunk's loads now: vmcnt drain happens at the NEXT
        // iteration's first barrier, after the whole compute phase.
        int nk = kc < 35 ? kc + 1 : 35;
        kreg = *(const uint4*)(kptr + (size_t)nk * 2048);
        vreg = *(const uint4*)(vptr + nk * 64);

        // S^T: tile t covers keys t*16+quad*4+r, col q=lm
        f32x4 s[4];
        for (int t = 0; t < 4; t++) {
            short8 kf = *(const short8*)&Ksh[t * 16 + lm][quad * 8];
            s[t] = MFMA16(kf, qf, Z4);
        }

        // p = exp2(s); accumulate per-lane l; pack via v_cvt_pk_bf16_f32.
        for (int t = 0; t < 4; t++) {
            float p0 = exp2f(s[t][0]);
            float p1 = exp2f(s[t][1]);
            float p2 = exp2f(s[t][2]);
            float p3 = exp2f(s[t][3]);
            l += (p0 + p1) + (p2 + p3);
            uint2 pk;
            pk.x = cvt_pk_bf16(p0, p1);
            pk.y = cvt_pk_bf16(p2, p3);
            *(uint2*)&Pl[w][lm][t * 16 + quad * 4] = pk;
        }
        asm volatile("s_waitcnt lgkmcnt(0)" ::: "memory");  // wave's P writes done

        // O^T += V^T * P^T per 32-key group
        for (int g = 0; g < 2; g++) {
            short8 pf = *(const short8*)&Pl[w][lm][g * 32 + quad * 8];
            for (int dt = 0; dt < 2; dt++) {
                short8 vf = *(const short8*)&Vsh[dt * 16 + lm][g * 32 + quad * 8];
                o_acc[dt] = MFMA16(vf, pf, o_acc[dt]);
            }
        }
    }

    // Quads hold disjoint key subsets for the same q=lm: reduce l across quads.
    l += __shfl_xor(l, 16, 64);
    l += __shfl_xor(l, 32, 64);
    float rl = 1.f / l;
    for (int dt = 0; dt < 2; dt++) {
        uint2 o;
        o.x = cvt_pk_bf16(o_acc[dt][0] * rl, o_acc[dt][1] * rl);
        o.y = cvt_pk_bf16(o_acc[dt][2] * rl, o_acc[dt][3] * rl);
        *(uint2*)(O + ((size_t)b * 2304 + qrow) * 256 + h * 32 + dt * 16 + quad * 4)
            = o;
    }
}

// ---------------------------------------------------------------------------
// LayerNorm over C=256 fused with transpose to channel-major:
//   Z[18432][256] -> Yt[(half*4+b)*256 + c][2304]  (spatial innermost)
// Block = 32 toks. Thread (tok_l = tid>>3, cq = tid&7) owns 32 c of one tok.
// LDS tile T[c][col] with rotation col = tok_l + 4*(c>>5) to spread banks;
// pass 2 reads uint2 (4 toks) and stores 8B contiguous runs.
// ---------------------------------------------------------------------------
__global__ __launch_bounds__(256) void lnt_kernel(
    const ushort* __restrict__ Z, const ushort* __restrict__ G1,
    const ushort* __restrict__ B1, const ushort* __restrict__ G2,
    const ushort* __restrict__ B2, ushort* __restrict__ Yt)
{
    __shared__ ushort T[256][72];   // 36 KB

    const int tid = threadIdx.x;
    const int tok0 = blockIdx.x * 32;
    const int half = (tok0 >= 9216) ? 1 : 0;
    const int tr = tok0 - half * 9216;
    const int bb = tr / 2304;
    const int tokb = tr - bb * 2304;

    const int tok_l = tid >> 3;      // 0..31
    const int cq = tid & 7;          // c-chunk of 32

    const ushort* zp = Z + ((size_t)(tok0 + tok_l)) * 256 + cq * 32;
    uint dd[16];
    for (int i = 0; i < 4; i++) {
        uint4 v = *(const uint4*)(zp + i * 8);
        dd[i * 4 + 0] = v.x; dd[i * 4 + 1] = v.y;
        dd[i * 4 + 2] = v.z; dd[i * 4 + 3] = v.w;
    }
    float s = 0.f, q = 0.f;
    for (int e = 0; e < 16; e++) {
        float x0 = bf2f((ushort)dd[e]);
        float x1 = bf2f((ushort)(dd[e] >> 16));
        s += x0 + x1;
        q += x0 * x0 + x1 * x1;
    }
    s += __shfl_xor(s, 1, 64); q += __shfl_xor(q, 1, 64);
    s += __shfl_xor(s, 2, 64); q += __shfl_xor(q, 2, 64);
    s += __shfl_xor(s, 4, 64); q += __shfl_xor(q, 4, 64);
    float mu = s * (1.f / 256.f);
    float var = q * (1.f / 256.f) - mu * mu;
    float rs = rsqrtf(var + 1e-5f);

    const ushort* Gs = half ? G2 : G1;
    const ushort* Bs = half ? B2 : B1;
    const int col = tok_l + 4 * cq;          // rotation: c>>5 == cq for this thread

    for (int i = 0; i < 4; i++) {
        int cb = cq * 32 + i * 8;
        uint4 gv = *(const uint4*)(Gs + cb);
        uint4 bv = *(const uint4*)(Bs + cb);
        uint gg[4] = {gv.x, gv.y, gv.z, gv.w};
        uint bw[4] = {bv.x, bv.y, bv.z, bv.w};
        for (int k = 0; k < 4; k++) {
            uint u = dd[i * 4 + k];
            float x0 = bf2f((ushort)u), x1 = bf2f((ushort)(u >> 16));
            float y0 = (x0 - mu) * rs * bf2f((ushort)gg[k]) + bf2f((ushort)bw[k]);
            float y1 = (x1 - mu) * rs * bf2f((ushort)(gg[k] >> 16))
                     + bf2f((ushort)(bw[k] >> 16));
            int c = cb + 2 * k;
            T[c][col]     = f2bf(y0);
            T[c + 1][col] = f2bf(y1);
        }
    }
    __syncthreads();

    // Pass 2: write out. Thread (c_row = tid>>3, tq = (tid&7)*4): 8 c rows,
    // 4 toks each as uint2. Rotation offset for c-group i is 4*i.
    const int c_row = tid >> 3;          // 0..31
    const int tq = (tid & 7) * 4;        // 0..28
    const size_t obase = ((size_t)((half * 4 + bb) * 256)) * 2304 + tokb + tq;
    for (int i = 0; i < 8; i++) {
        int c = c_row + 32 * i;          // c>>5 == i
        uint2 v = *(const uint2*)&T[c][tq + 4 * i];
        *(uint2*)(Yt + obase + (size_t)c * 2304) = v;
    }
}

// ---------------------------------------------------------------------------
// Bilinear 2x upsample from channel-major Yt[bc][48*48] (spatial contiguous).
// Each thread: one oj-pair (oj=2m, 2m+1) -> float2 store. Weights for the
// pair need row values {m-1, m, m+1} (clamped): 6 coalesced u16 reads.
// bc order matches output [B,C,96,96] for both halves.
// ---------------------------------------------------------------------------
__global__ __launch_bounds__(256) void upsample_kernel(
    const ushort* __restrict__ Yt, float* __restrict__ out)
{
    int idx = blockIdx.x * 256 + threadIdx.x;    // 36864 blocks
    int m  = idx % 48;
    int t  = idx / 48;
    int oi = t % 96;
    int bc = t / 96;                 // 0..2047

    float fi = oi * 0.5f - 0.25f;
    int i0 = (int)floorf(fi);
    float wi = fi - (float)i0;
    int i1 = i0 + 1 < 47 ? i0 + 1 : 47;
    i0 = i0 > 0 ? i0 : 0;
    int jm = m - 1 > 0 ? m - 1 : 0;
    int jp = m + 1 < 47 ? m + 1 : 47;

    const ushort* r0 = Yt + (size_t)bc * 2304 + i0 * 48;
    const ushort* r1 = Yt + (size_t)bc * 2304 + i1 * 48;
    float a0 = bf2f(r0[jm]), b0 = bf2f(r0[m]), c0 = bf2f(r0[jp]);
    float a1 = bf2f(r1[jm]), b1 = bf2f(r1[m]), c1 = bf2f(r1[jp]);
    float u = 1.f - wi;
    float ha = u * a0 + wi * a1;
    float hb = u * b0 + wi * b1;
    float hc = u * c0 + wi * c1;
    float2 o;
    o.x = 0.25f * ha + 0.75f * hb;
    o.y = 0.75f * hb + 0.25f * hc;
    *(float2*)(out + (size_t)bc * 9216 + oi * 96 + m * 2) = o;
}

// ---------------------------------------------------------------------------
extern "C" void kernel_launch(void* const* d_in, const int* in_sizes, int n_in,
                              void* d_out, int out_size, void* d_ws, size_t ws_size,
                              hipStream_t stream)
{
    (void)in_sizes; (void)n_in; (void)out_size; (void)ws_size;

    // ---- Buffer plan (stream-order-safe reuse; ~29.4 MB of ws) ----
    ushort* ws  = (ushort*)d_ws;
    ushort* Q1  = ws;                         // [9216,256]
    ushort* Q2  = Q1  + 2359296;              // contiguous with Q1
    ushort* KV1 = Q2  + 2359296;              // Kh1 + Vt1
    ushort* KV2 = KV1 + 4718592;              // Kh2 + Vt2
    ushort* wc  = KV2 + 4718592;              // canonical params
    int*    dflag = (int*)(wc + 525824);

    ushort* cqkv1w = wc;                      // [768,256] = q1w ++ kv1w
    ushort* cqkv2w = wc + 196608;             // [768,256] = q2w ++ kv2w
    ushort* cp1w  = wc + 393216;
    ushort* cp2w  = wc + 458752;
    ushort* cp1b  = wc + 524288;
    ushort* cp2b  = wc + 524544;
    ushort* cg1   = wc + 524800;
    ushort* cb1   = wc + 525056;
    ushort* cg2   = wc + 525312;
    ushort* cb2   = wc + 525568;

    float*  outf = (float*)d_out;
    ushort* O1  = (ushort*)d_out;             // bf16 staging (dead pre-upsample)
    ushort* O2  = O1 + 2359296;               // contiguous with O1
    ushort* Xb1 = O2 + 2359296;               // bf16 x1 (dead after QKV gemm)
    ushort* Xb2 = Xb1 + 2359296;              // contiguous with Xb1
    ushort* Z1  = KV2;                        // KV2 dead after attn (launch order)
    ushort* Yt  = Q1;                         // Q1+Q2 dead after attn: 9.4 MB
    (void)Q2; (void)O2; (void)Xb2;

    dim3 blk(256);
    sniff_kernel<<<dim3(1), dim3(64), 0, stream>>>((const ushort*)d_in[0], dflag);
    convert_params<<<dim3(2054), blk, 0, stream>>>(
        d_in[2], d_in[3], d_in[4], d_in[5], d_in[8], d_in[10],
        d_in[9], d_in[11], d_in[12], d_in[13], d_in[14], d_in[15],
        wc, dflag);
    convert_x<<<dim3(2304), blk, 0, stream>>>(d_in[0], d_in[1], Xb1, Xb2, dflag);

    // Merged Q+KV projections for BOTH inputs (M=18432, N=768):
    // Q scaled by scale*log2e, Kh per-head, Vt transposed.
    gemm_bt<<<dim3(288, 12), blk, 0, stream>>>(Xb1, cqkv1w, Q1, nullptr,
        18432, 768, 256, 0, dflag, 0, 1, KV1, KV1 + 2359296,
        cqkv2w, nullptr, KV2, KV2 + 2359296, 9216);

    // Both cross attentions in one dispatch (grid.y 0..31 = x1->x2 side,
    // 32..63 = x2->x1 side).
    attn_kernel<<<dim3(36, 64), blk, 0, stream>>>(
        Q1, KV2, KV2 + 2359296, O1,
        Q2, KV1, KV1 + 2359296, O2);

    // Merged output projection + bias + ReLU (M=18432).
    gemm_bt<<<dim3(288, 4), blk, 0, stream>>>(O1, cp1w, Z1, cp1b,
        18432, 256, 256, 1, dflag, 0, 0, nullptr, nullptr,
        cp2w, cp2b, nullptr, nullptr, 9216);

    // LayerNorm + transpose to channel-major (18432 tokens, 32/block).
    lnt_kernel<<<dim3(576), blk, 0, stream>>>(Z1, cg1, cb1, cg2, cb2, Yt);

    // Bilinear 2x upsample into d_out (float32, both outputs, float2/thread).
    upsample_kernel<<<dim3(36864), blk, 0, stream>>>(Yt, outf);
}

// Round 4
// 292.122 us; speedup vs baseline: 1.6189x; 1.0117x over previous
//
#include <hip/hip_runtime.h>
#include <math.h>

// ---------------------------------------------------------------------------
// CrossPath: dual cross-attention block, MI355X (gfx950).
//   B=4, N=2304, C=256, H=8, D=32, out = 2 x [B,C,96,96] float32
// Inputs float32 (runtime-sniffed). Internal: bf16 MFMA, fp32 accumulation.
// R11 (= R10 re-land): attn on v_mfma_f32_32x32x16_bf16, 32 q-rows/wave
// (128 q/block), P^T redistribution fully in-register via
// __builtin_amdgcn_permlane32_swap (documented gfx950 builtin; replaces the
// undocumented inline-asm form that may have killed the R10 container).
// No P LDS round-trip; K/V LDS reads serve 2x the q-work. LDS 19.9->9.7KB.
// ---------------------------------------------------------------------------

typedef __attribute__((ext_vector_type(8))) short short8;   // 8 bf16 = 4 VGPRs
typedef __attribute__((ext_vector_type(4))) float f32x4;
typedef __attribute__((ext_vector_type(16))) float f32x16;
typedef __attribute__((ext_vector_type(2))) unsigned uint32x2;

#define MFMA16(a, b, c) __builtin_amdgcn_mfma_f32_16x16x32_bf16((a), (b), (c), 0, 0, 0)
#define MFMA32(a, b, c) __builtin_amdgcn_mfma_f32_32x32x16_bf16((a), (b), (c), 0, 0, 0)

__device__ __forceinline__ float bf2f(ushort u) {
    union { unsigned u; float f; } x; x.u = ((unsigned)u) << 16; return x.f;
}
__device__ __forceinline__ ushort f2bf(float f) {
    union { float f; unsigned u; } x; x.f = f;
    unsigned u = x.u;
    return (ushort)((u + 0x7fffu + ((u >> 16) & 1u)) >> 16);   // RNE
}
// HW packed RNE conversion: D = {bf16(b)<<16 | bf16(a)}
__device__ __forceinline__ unsigned cvt_pk_bf16(float a, float b) {
    unsigned r;
    asm("v_cvt_pk_bf16_f32 %0, %1, %2" : "=v"(r) : "v"(a), "v"(b));
    return r;
}
// Exchange upper 32 lanes of a with lower 32 lanes of b (gfx950 builtin).
__device__ __forceinline__ void plswap(unsigned &a, unsigned &b) {
    uint32x2 r = __builtin_amdgcn_permlane32_swap(a, b, false, false);
    a = r[0]; b = r[1];
}

// ---------------------------------------------------------------------------
// Dtype sniffer: flag=1 means f32 inputs.
// ---------------------------------------------------------------------------
__global__ void sniff_kernel(const ushort* __restrict__ x, int* __restrict__ flag)
{
    int lane = threadIdx.x;
    ushort u = x[lane * 2];
    int e = (u >> 7) & 0xFF;
    int outlier = (e < 100 || e > 135) ? 1 : 0;
    unsigned long long m = __ballot(outlier);
    if (lane == 0) *flag = (__popcll(m) >= 16) ? 1 : 0;
}

// ---------------------------------------------------------------------------
// Canonicalize all 12 weight/param arrays to bf16 at fixed offsets in ws.
// ---------------------------------------------------------------------------
__global__ __launch_bounds__(256) void convert_params(
    const void* s0, const void* s1, const void* s2, const void* s3,
    const void* s4, const void* s5, const void* s6, const void* s7,
    const void* s8, const void* s9, const void* s10, const void* s11,
    ushort* __restrict__ dst, const int* __restrict__ flag)
{
    int idx = blockIdx.x * 256 + threadIdx.x;
    if (idx >= 525824) return;
    const void* src; int off;
    if      (idx < 65536)  { src = s0;  off = idx; }
    else if (idx < 196608) { src = s1;  off = idx - 65536; }
    else if (idx < 262144) { src = s2;  off = idx - 196608; }
    else if (idx < 393216) { src = s3;  off = idx - 262144; }
    else if (idx < 458752) { src = s4;  off = idx - 393216; }
    else if (idx < 524288) { src = s5;  off = idx - 458752; }
    else if (idx < 524544) { src = s6;  off = idx - 524288; }
    else if (idx < 524800) { src = s7;  off = idx - 524544; }
    else if (idx < 525056) { src = s8;  off = idx - 524800; }
    else if (idx < 525312) { src = s9;  off = idx - 525056; }
    else if (idx < 525568) { src = s10; off = idx - 525312; }
    else                   { src = s11; off = idx - 525568; }
    ushort v = (*flag) ? f2bf(((const float*)src)[off])
                       : ((const ushort*)src)[off];
    dst[idx] = v;
}

// ---------------------------------------------------------------------------
// Pre-convert x1/x2 -> bf16 once (8 elems/thread).
// ---------------------------------------------------------------------------
__global__ __launch_bounds__(256) void convert_x(
    const void* __restrict__ x1, const void* __restrict__ x2,
    ushort* __restrict__ o1, ushort* __restrict__ o2,
    const int* __restrict__ flag)
{
    int idx = blockIdx.x * 256 + threadIdx.x;      // 2304 blocks -> 589824 thr
    int which = idx >= 294912;
    int off = (which ? idx - 294912 : idx) * 8;
    const void* src = which ? x2 : x1;
    ushort* dst = which ? o2 : o1;
    if (*flag) {
        const float* p = (const float*)src + off;
        float4 a = *(const float4*)p;
        float4 c = *(const float4*)(p + 4);
        uint4 u;
        u.x = cvt_pk_bf16(a.x, a.y);
        u.y = cvt_pk_bf16(a.z, a.w);
        u.z = cvt_pk_bf16(c.x, c.y);
        u.w = cvt_pk_bf16(c.z, c.w);
        *(uint4*)(dst + off) = u;
    } else {
        *(uint4*)(dst + off) = *(const uint4*)((const ushort*)src + off);
    }
}

// ---------------------------------------------------------------------------
// GEMM: C[M,N] = A[M,K]*W[N,K]^T, bf16 MFMA 16x16x32, tile 64x64, 4 waves.
// Two stacked problems (rows [0,mhalf) use W/bias/Kh/Vt, rows [mhalf,M) use
// W2/bias2/Kh2/Vt2). mode 0: plain C (+bias/relu). mode 1 (merged QKV,
// N=768): col<256 -> Q row-major SCALED by scale*log2e; col<512 ->
// Kh[b][h][tok][32]; else -> Vt[b][h][d][2304].
// ---------------------------------------------------------------------------
__global__ __launch_bounds__(256) void gemm_bt(
    const void* __restrict__ Ain, const ushort* __restrict__ W,
    ushort* __restrict__ C, const ushort* __restrict__ bias,
    int M, int N, int K, int relu, const int* __restrict__ dflag, int a_ext,
    int mode, ushort* __restrict__ Kh, ushort* __restrict__ Vt,
    const ushort* __restrict__ W2, const ushort* __restrict__ bias2,
    ushort* __restrict__ Kh2, ushort* __restrict__ Vt2, int mhalf)
{
    __shared__ __align__(16) ushort As[64][40];
    __shared__ __align__(16) ushort Ws[64][40];

    const int m0 = blockIdx.x * 64;
    const int n0 = blockIdx.y * 64;
    const int tid = threadIdx.x;
    const int w = tid >> 6;
    const int lane = tid & 63;
    const int lm = lane & 15;
    const int quad = lane >> 4;
    const int a32 = a_ext ? *dflag : 0;

    const int side = (mhalf && m0 >= mhalf) ? 1 : 0;
    const ushort* Wu = side ? W2 : W;
    const ushort* bu = side ? bias2 : bias;
    ushort* Khu = side ? Kh2 : Kh;
    ushort* Vtu = side ? Vt2 : Vt;

    const f32x4 Z4 = {0.f, 0.f, 0.f, 0.f};
    f32x4 acc[4];
    for (int j = 0; j < 4; j++) acc[j] = Z4;

    const ushort* A16 = (const ushort*)Ain;
    const float*  A32 = (const float*)Ain;
    const int row = tid >> 2, off = (tid & 3) * 8;

    for (int k0 = 0; k0 < K; k0 += 32) {
        __syncthreads();
        if (a32) {
            const float* p0 = A32 + (size_t)(m0 + row) * K + k0 + off;
            float4 f0 = *(const float4*)p0;
            float4 f1 = *(const float4*)(p0 + 4);
            uint4 t0;
            t0.x = cvt_pk_bf16(f0.x, f0.y);
            t0.y = cvt_pk_bf16(f0.z, f0.w);
            t0.z = cvt_pk_bf16(f1.x, f1.y);
            t0.w = cvt_pk_bf16(f1.z, f1.w);
            *(uint4*)&As[row][off] = t0;
        } else {
            *(uint4*)&As[row][off] =
                *(const uint4*)(A16 + (size_t)(m0 + row) * K + k0 + off);
        }
        *(uint4*)&Ws[row][off] =
            *(const uint4*)(Wu + (size_t)(n0 + row) * K + k0 + off);
        __syncthreads();

        short8 af = *(const short8*)&As[w * 16 + lm][quad * 8];
        for (int nt = 0; nt < 4; nt++) {
            short8 wf = *(const short8*)&Ws[nt * 16 + lm][quad * 8];
            acc[nt] = MFMA16(af, wf, acc[nt]);
        }
    }

    const int grow = m0 + w * 16 + quad * 4;     // global C row (4 consecutive)
    const int grel = grow - (side ? mhalf : 0);  // row within half (Kh/Vt)
    if (mode == 1) {
        const float QSC = 0.17677669529663687f * 1.4426950408889634f;
        int bb = grel / 2304;
        int tok = grel - bb * 2304;              // 4-aligned; same bb for r=0..3
        for (int nt = 0; nt < 4; nt++) {
            int col = n0 + nt * 16 + lm;
            if (col < 256) {
                for (int r = 0; r < 4; r++)
                    C[(size_t)(grow + r) * 256 + col] = f2bf(acc[nt][r] * QSC);
            } else if (col < 512) {
                int c2 = col - 256, hh = c2 >> 5, d = c2 & 31;
                for (int r = 0; r < 4; r++)
                    Khu[(((size_t)bb * 8 + hh) * 2304 + tok + r) * 32 + d] = f2bf(acc[nt][r]);
            } else {
                int c2 = col - 512, hh = c2 >> 5, d = c2 & 31;
                uint2 o;
                o.x = cvt_pk_bf16(acc[nt][0], acc[nt][1]);
                o.y = cvt_pk_bf16(acc[nt][2], acc[nt][3]);
                *(uint2*)&Vtu[(((size_t)bb * 8 + hh) * 32 + d) * 2304 + tok] = o;
            }
        }
    } else {
        for (int nt = 0; nt < 4; nt++) {
            int col = n0 + nt * 16 + lm;
            float bv = bu ? bf2f(bu[col]) : 0.f;
            for (int r = 0; r < 4; r++) {
                float v = acc[nt][r] + bv;
                if (relu) v = fmaxf(v, 0.f);
                C[(size_t)(grow + r) * N + col] = f2bf(v);
            }
        }
    }
}

// ---------------------------------------------------------------------------
// Flash cross-attention, S^T form on 32x32x16 MFMA, no-max softmax
// (p = exp2(s), Q pre-scaled by scale*log2e in the QKV GEMM).
// Block = 4 waves x 32 q-rows (128 q), 64-key chunks, both directions in one
// dispatch. S^T: A=K (rows=keys), B=Q (cols=q). C/D layout (verified):
// col=lane&31, row=(reg&3)+8*(reg>>2)+4*(lane>>5). The PV B-operand needs
// keys regrouped across lane-halves: cvt_pk pairs + 4x permlane32_swap
// build the P fragments fully in-register (no P LDS round-trip).
// Q:[B,2304,256]; Kh:[b][h][tok][32]; Vt:[b][h][d][2304]; O:[B,2304,256].
// ---------------------------------------------------------------------------
__global__ __launch_bounds__(256) void attn_kernel(
    const ushort* __restrict__ Qa, const ushort* __restrict__ Kha,
    const ushort* __restrict__ Vta, ushort* __restrict__ Oa,
    const ushort* __restrict__ Qb, const ushort* __restrict__ Khb2,
    const ushort* __restrict__ Vtb2, ushort* __restrict__ Ob)
{
    __shared__ __align__(16) ushort Ksh[64][40];   // [key][d]
    __shared__ __align__(16) ushort Vsh[32][72];   // [d][tok]

    const int qb = blockIdx.x;            // 18 q-blocks of 128
    const int side = blockIdx.y >> 5;
    const int bh = blockIdx.y & 31;
    const ushort* Q  = side ? Qb   : Qa;
    const ushort* Kh = side ? Khb2 : Kha;
    const ushort* Vt = side ? Vtb2 : Vta;
    ushort* O        = side ? Ob   : Oa;

    const int b = bh >> 3, h = bh & 7;
    const int tid = threadIdx.x;
    const int w = tid >> 6, lane = tid & 63;
    const int l31 = lane & 31, hl = lane >> 5;

    // Q B-frags: lane holds q-col = l31, d = 16*dstep + hl*8 + j (persistent)
    const int qrow = qb * 128 + w * 32 + l31;
    const ushort* qp = Q + ((size_t)b * 2304 + qrow) * 256 + h * 32 + hl * 8;
    short8 qf0 = *(const short8*)qp;          // d = hl*8 + j
    short8 qf1 = *(const short8*)(qp + 16);   // d = 16 + hl*8 + j

    f32x16 o_acc;
    #pragma unroll
    for (int i = 0; i < 16; i++) o_acc[i] = 0.f;
    const f32x16 Z16 = o_acc;
    float l = 0.f;                            // per-lane partial denominator

    const ushort* Khb = Kh + (size_t)bh * 2304 * 32;
    const ushort* Vtb = Vt + (size_t)bh * 32 * 2304;
    const int ks_row = tid >> 2, ks_off = (tid & 3) * 8;
    const int vs_row = tid >> 3, vs_off = (tid & 7) * 8;

    const ushort* kptr = Khb + (size_t)ks_row * 32 + ks_off;
    const ushort* vptr = Vtb + (size_t)vs_row * 2304 + vs_off;
    uint4 kreg = *(const uint4*)kptr;
    uint4 vreg = *(const uint4*)vptr;

    for (int kc = 0; kc < 36; kc++) {
        __syncthreads();
        *(uint4*)&Ksh[ks_row][ks_off] = kreg;
        *(uint4*)&Vsh[vs_row][vs_off] = vreg;
        __syncthreads();

        // issue next chunk's loads now; the vmcnt drain lands at the NEXT
        // iteration's barrier, after this iteration's compute.
        int nk = kc < 35 ? kc + 1 : 35;
        kreg = *(const uint4*)(kptr + (size_t)nk * 2048);
        vreg = *(const uint4*)(vptr + nk * 64);

        #pragma unroll
        for (int t = 0; t < 2; t++) {
            // S^T tile t: keys 32t..32t+31, cols = this wave's 32 q.
            short8 kf0 = *(const short8*)&Ksh[t * 32 + l31][hl * 8];
            short8 kf1 = *(const short8*)&Ksh[t * 32 + l31][16 + hl * 8];
            f32x16 s = MFMA32(kf0, qf0, Z16);
            s = MFMA32(kf1, qf1, s);

            // p = exp2(s); reg r holds key (r&3)+8*(r>>2)+4*hl (within tile).
            float p[16];
            #pragma unroll
            for (int i = 0; i < 16; i++) p[i] = exp2f(s[i]);
            l += (((p[0] + p[1]) + (p[2] + p[3])) + ((p[4] + p[5]) + (p[6] + p[7])))
               + (((p[8] + p[9]) + (p[10] + p[11])) + ((p[12] + p[13]) + (p[14] + p[15])));

            // Pack consecutive-key pairs, then lane-half exchange:
            // hl=0 lanes: c0={k0,1} c1={k2,3} c2={k8,9} c3={k10,11}
            // hl=1 lanes: same +4.  swap(a,b): a.hi <-> b.lo.
            unsigned c0 = cvt_pk_bf16(p[0],  p[1]);
            unsigned c1 = cvt_pk_bf16(p[2],  p[3]);
            unsigned c2 = cvt_pk_bf16(p[4],  p[5]);
            unsigned c3 = cvt_pk_bf16(p[6],  p[7]);
            unsigned c4 = cvt_pk_bf16(p[8],  p[9]);
            unsigned c5 = cvt_pk_bf16(p[10], p[11]);
            unsigned c6 = cvt_pk_bf16(p[12], p[13]);
            unsigned c7 = cvt_pk_bf16(p[14], p[15]);
            plswap(c0, c2);   // c0: {k0k1|k8k9}   c2: {k4k5|k12k13}
            plswap(c1, c3);   // c1: {k2k3|k10k11} c3: {k6k7|k14k15}
            plswap(c4, c6);   // keys 16-31 analogously
            plswap(c5, c7);

            union { unsigned u[4]; short8 s8; } pA, pB;
            pA.u[0] = c0; pA.u[1] = c1; pA.u[2] = c2; pA.u[3] = c3;
            pB.u[0] = c4; pB.u[1] = c5; pB.u[2] = c6; pB.u[3] = c7;

            // O^T += V^T * P^T (A: rows=d=l31, k=keys; B: cols=q, k=keys)
            short8 vf0 = *(const short8*)&Vsh[l31][t * 32 + hl * 8];
            short8 vf1 = *(const short8*)&Vsh[l31][t * 32 + 16 + hl * 8];
            o_acc = MFMA32(vf0, pA.s8, o_acc);
            o_acc = MFMA32(vf1, pB.s8, o_acc);
        }
    }

    // Lane halves hold disjoint key subsets for the same q: reduce l.
    l += __shfl_xor(l, 32, 64);
    float rl = 1.f / l;
    // o_acc reg r: d = (r&3) + 8*(r>>2) + 4*hl, q = l31.
    ushort* op = O + ((size_t)b * 2304 + qrow) * 256 + h * 32 + hl * 4;
    #pragma unroll
    for (int g = 0; g < 4; g++) {
        uint2 o;
        o.x = cvt_pk_bf16(o_acc[4 * g] * rl, o_acc[4 * g + 1] * rl);
        o.y = cvt_pk_bf16(o_acc[4 * g + 2] * rl, o_acc[4 * g + 3] * rl);
        *(uint2*)(op + 8 * g) = o;
    }
}

// ---------------------------------------------------------------------------
// LayerNorm over C=256 fused with transpose to channel-major:
//   Z[18432][256] -> Yt[(half*4+b)*256 + c][2304]  (spatial innermost)
// ---------------------------------------------------------------------------
__global__ __launch_bounds__(256) void lnt_kernel(
    const ushort* __restrict__ Z, const ushort* __restrict__ G1,
    const ushort* __restrict__ B1, const ushort* __restrict__ G2,
    const ushort* __restrict__ B2, ushort* __restrict__ Yt)
{
    __shared__ ushort T[256][72];   // 36 KB

    const int tid = threadIdx.x;
    const int tok0 = blockIdx.x * 32;
    const int half = (tok0 >= 9216) ? 1 : 0;
    const int tr = tok0 - half * 9216;
    const int bb = tr / 2304;
    const int tokb = tr - bb * 2304;

    const int tok_l = tid >> 3;      // 0..31
    const int cq = tid & 7;          // c-chunk of 32

    const ushort* zp = Z + ((size_t)(tok0 + tok_l)) * 256 + cq * 32;
    uint dd[16];
    for (int i = 0; i < 4; i++) {
        uint4 v = *(const uint4*)(zp + i * 8);
        dd[i * 4 + 0] = v.x; dd[i * 4 + 1] = v.y;
        dd[i * 4 + 2] = v.z; dd[i * 4 + 3] = v.w;
    }
    float s = 0.f, q = 0.f;
    for (int e = 0; e < 16; e++) {
        float x0 = bf2f((ushort)dd[e]);
        float x1 = bf2f((ushort)(dd[e] >> 16));
        s += x0 + x1;
        q += x0 * x0 + x1 * x1;
    }
    s += __shfl_xor(s, 1, 64); q += __shfl_xor(q, 1, 64);
    s += __shfl_xor(s, 2, 64); q += __shfl_xor(q, 2, 64);
    s += __shfl_xor(s, 4, 64); q += __shfl_xor(q, 4, 64);
    float mu = s * (1.f / 256.f);
    float var = q * (1.f / 256.f) - mu * mu;
    float rs = rsqrtf(var + 1e-5f);

    const ushort* Gs = half ? G2 : G1;
    const ushort* Bs = half ? B2 : B1;
    const int col = tok_l + 4 * cq;          // rotation: c>>5 == cq here

    for (int i = 0; i < 4; i++) {
        int cb = cq * 32 + i * 8;
        uint4 gv = *(const uint4*)(Gs + cb);
        uint4 bv = *(const uint4*)(Bs + cb);
        uint gg[4] = {gv.x, gv.y, gv.z, gv.w};
        uint bw[4] = {bv.x, bv.y, bv.z, bv.w};
        for (int k = 0; k < 4; k++) {
            uint u = dd[i * 4 + k];
            float x0 = bf2f((ushort)u), x1 = bf2f((ushort)(u >> 16));
            float y0 = (x0 - mu) * rs * bf2f((ushort)gg[k]) + bf2f((ushort)bw[k]);
            float y1 = (x1 - mu) * rs * bf2f((ushort)(gg[k] >> 16))
                     + bf2f((ushort)(bw[k] >> 16));
            int c = cb + 2 * k;
            T[c][col]     = f2bf(y0);
            T[c + 1][col] = f2bf(y1);
        }
    }
    __syncthreads();

    // Pass 2: thread (c_row = tid>>3, tq = (tid&7)*4): 8 c rows, 4 toks each.
    const int c_row = tid >> 3;          // 0..31
    const int tq = (tid & 7) * 4;        // 0..28
    const size_t obase = ((size_t)((half * 4 + bb) * 256)) * 2304 + tokb + tq;
    for (int i = 0; i < 8; i++) {
        int c = c_row + 32 * i;          // c>>5 == i
        uint2 v = *(const uint2*)&T[c][tq + 4 * i];
        *(uint2*)(Yt + obase + (size_t)c * 2304) = v;
    }
}

// ---------------------------------------------------------------------------
// Bilinear 2x upsample from channel-major Yt[bc][48*48] (spatial contiguous).
// Each thread: one oj-pair -> float2 store.
// ---------------------------------------------------------------------------
__global__ __launch_bounds__(256) void upsample_kernel(
    const ushort* __restrict__ Yt, float* __restrict__ out)
{
    int idx = blockIdx.x * 256 + threadIdx.x;    // 36864 blocks
    int m  = idx % 48;
    int t  = idx / 48;
    int oi = t % 96;
    int bc = t / 96;                 // 0..2047

    float fi = oi * 0.5f - 0.25f;
    int i0 = (int)floorf(fi);
    float wi = fi - (float)i0;
    int i1 = i0 + 1 < 47 ? i0 + 1 : 47;
    i0 = i0 > 0 ? i0 : 0;
    int jm = m - 1 > 0 ? m - 1 : 0;
    int jp = m + 1 < 47 ? m + 1 : 47;

    const ushort* r0 = Yt + (size_t)bc * 2304 + i0 * 48;
    const ushort* r1 = Yt + (size_t)bc * 2304 + i1 * 48;
    float a0 = bf2f(r0[jm]), b0 = bf2f(r0[m]), c0 = bf2f(r0[jp]);
    float a1 = bf2f(r1[jm]), b1 = bf2f(r1[m]), c1 = bf2f(r1[jp]);
    float u = 1.f - wi;
    float ha = u * a0 + wi * a1;
    float hb = u * b0 + wi * b1;
    float hc = u * c0 + wi * c1;
    float2 o;
    o.x = 0.25f * ha + 0.75f * hb;
    o.y = 0.75f * hb + 0.25f * hc;
    *(float2*)(out + (size_t)bc * 9216 + oi * 96 + m * 2) = o;
}

// ---------------------------------------------------------------------------
extern "C" void kernel_launch(void* const* d_in, const int* in_sizes, int n_in,
                              void* d_out, int out_size, void* d_ws, size_t ws_size,
                              hipStream_t stream)
{
    (void)in_sizes; (void)n_in; (void)out_size; (void)ws_size;

    // ---- Buffer plan (stream-order-safe reuse; ~29.4 MB of ws) ----
    ushort* ws  = (ushort*)d_ws;
    ushort* Q1  = ws;                         // [9216,256]
    ushort* Q2  = Q1  + 2359296;              // contiguous with Q1
    ushort* KV1 = Q2  + 2359296;              // Kh1 + Vt1
    ushort* KV2 = KV1 + 4718592;              // Kh2 + Vt2
    ushort* wc  = KV2 + 4718592;              // canonical params
    int*    dflag = (int*)(wc + 525824);

    ushort* cqkv1w = wc;                      // [768,256] = q1w ++ kv1w
    ushort* cqkv2w = wc + 196608;             // [768,256] = q2w ++ kv2w
    ushort* cp1w  = wc + 393216;
    ushort* cp2w  = wc + 458752;
    ushort* cp1b  = wc + 524288;
    ushort* cp2b  = wc + 524544;
    ushort* cg1   = wc + 524800;
    ushort* cb1   = wc + 525056;
    ushort* cg2   = wc + 525312;
    ushort* cb2   = wc + 525568;

    float*  outf = (float*)d_out;
    ushort* O1  = (ushort*)d_out;             // bf16 staging (dead pre-upsample)
    ushort* O2  = O1 + 2359296;               // contiguous with O1
    ushort* Xb1 = O2 + 2359296;               // bf16 x1 (dead after QKV gemm)
    ushort* Xb2 = Xb1 + 2359296;              // contiguous with Xb1
    ushort* Z1  = KV2;                        // KV2 dead after attn (launch order)
    ushort* Yt  = Q1;                         // Q1+Q2 dead after attn: 9.4 MB
    (void)Q2; (void)O2; (void)Xb2;

    dim3 blk(256);
    sniff_kernel<<<dim3(1), dim3(64), 0, stream>>>((const ushort*)d_in[0], dflag);
    convert_params<<<dim3(2054), blk, 0, stream>>>(
        d_in[2], d_in[3], d_in[4], d_in[5], d_in[8], d_in[10],
        d_in[9], d_in[11], d_in[12], d_in[13], d_in[14], d_in[15],
        wc, dflag);
    convert_x<<<dim3(2304), blk, 0, stream>>>(d_in[0], d_in[1], Xb1, Xb2, dflag);

    // Merged Q+KV projections for BOTH inputs (M=18432, N=768):
    // Q scaled by scale*log2e, Kh per-head, Vt transposed.
    gemm_bt<<<dim3(288, 12), blk, 0, stream>>>(Xb1, cqkv1w, Q1, nullptr,
        18432, 768, 256, 0, dflag, 0, 1, KV1, KV1 + 2359296,
        cqkv2w, nullptr, KV2, KV2 + 2359296, 9216);

    // Both cross attentions in one dispatch (grid.y 0..31 = x1->x2 side,
    // 32..63 = x2->x1 side). 128 q per block.
    attn_kernel<<<dim3(18, 64), blk, 0, stream>>>(
        Q1, KV2, KV2 + 2359296, O1,
        Q2, KV1, KV1 + 2359296, O2);

    // Merged output projection + bias + ReLU (M=18432).
    gemm_bt<<<dim3(288, 4), blk, 0, stream>>>(O1, cp1w, Z1, cp1b,
        18432, 256, 256, 1, dflag, 0, 0, nullptr, nullptr,
        cp2w, cp2b, nullptr, nullptr, 9216);

    // LayerNorm + transpose to channel-major (18432 tokens, 32/block).
    lnt_kernel<<<dim3(576), blk, 0, stream>>>(Z1, cg1, cb1, cg2, cb2, Yt);

    // Bilinear 2x upsample into d_out (float32, both outputs, float2/thread).
    upsample_kernel<<<dim3(36864), blk, 0, stream>>>(Yt, outf);
}